// Round 6
// baseline (909.185 us; speedup 1.0000x reference)
//
#include <hip/hip_runtime.h>
#include <stdint.h>

typedef unsigned int u32;
typedef unsigned short u16;
typedef unsigned long long u64;
typedef __attribute__((ext_vector_type(8))) short bf16x8;
typedef __attribute__((ext_vector_type(4))) float f32x4;

#define HC 32
#define CPT 16   // points per wave in conv kernels

__device__ __forceinline__ float u2f(u32 u){ union{u32 i;float f;}v; v.i=u; return v.f; }
__device__ __forceinline__ u16 f2bf(float f){ union{float f;u32 i;}v; v.f=f; u32 i=v.i;
    return (u16)((i + 0x7FFFu + ((i>>16)&1u))>>16); }  // RNE
__device__ __forceinline__ short bfs(float f){ return (short)f2bf(f); }
__device__ __forceinline__ u32 packbf(float a, float b){ return (u32)f2bf(a) | ((u32)f2bf(b)<<16); }

// stage 26 sparse k-slices (skip k=13) of one 27x32x32 matrix, bf16x2 c-pairs:
// wl[kp*512 + (h*8+cc2)*32 + o] = pack(W[k][h*16+2cc2][o], W[k][h*16+2cc2+1][o])
__device__ __forceinline__ void stage_w26(const float* __restrict__ W, u32* __restrict__ wl, int nthr) {
    for (int i = threadIdx.x; i < 26*512; i += nthr) {
        int o = i & 31, row = (i >> 5) & 15, kp = i >> 9;
        int k = kp + (kp >= 13 ? 1 : 0);
        int c0 = (row >> 3)*16 + (row & 7)*2;
        wl[i] = packbf(W[k*1024 + c0*32 + o], W[k*1024 + (c0+1)*32 + o]);
    }
}

// ---- K1: y = x @ Wg1 + bg1 -> cv | gl  (MFMA, unchanged from round 5) ----
__global__ __launch_bounds__(256) void k1_mfma(
    const float* __restrict__ x, const float* __restrict__ Wg1, const float* __restrict__ bg1,
    float* __restrict__ cv, float* __restrict__ gl, long long N)
{
    const int lane = threadIdx.x & 63;
    const int m = lane & 15, g = lane >> 4;
    bf16x8 bw[4][2];
    #pragma unroll
    for (int no = 0; no < 4; ++no)
      #pragma unroll
      for (int kf = 0; kf < 2; ++kf)
        #pragma unroll
        for (int j = 0; j < 8; ++j)
            bw[no][kf][j] = bfs(Wg1[(kf*32 + g*8 + j)*64 + no*16 + m]);
    float bias4[4];
    #pragma unroll
    for (int no = 0; no < 4; ++no) bias4[no] = bg1[no*16 + m];

    const long long wave = (long long)blockIdx.x*4 + (threadIdx.x>>6);
    long long t0 = wave * 4;
    #pragma unroll 1
    for (long long t = t0; t < t0+4; ++t) {
        long long p0 = t*16;
        if (p0 >= N) break;
        long long pr_a = p0 + m; if (pr_a > N-1) pr_a = N-1;
        const float4* xr = (const float4*)(x + pr_a*64);
        bf16x8 aw[2];
        #pragma unroll
        for (int kf = 0; kf < 2; ++kf) {
            float4 lo = xr[kf*8 + g*2];
            float4 hi = xr[kf*8 + g*2 + 1];
            aw[kf][0]=bfs(lo.x); aw[kf][1]=bfs(lo.y); aw[kf][2]=bfs(lo.z); aw[kf][3]=bfs(lo.w);
            aw[kf][4]=bfs(hi.x); aw[kf][5]=bfs(hi.y); aw[kf][6]=bfs(hi.z); aw[kf][7]=bfs(hi.w);
        }
        #pragma unroll
        for (int no = 0; no < 4; ++no) {
            f32x4 acc = {0.f,0.f,0.f,0.f};
            acc = __builtin_amdgcn_mfma_f32_16x16x32_bf16(aw[0], bw[no][0], acc, 0,0,0);
            acc = __builtin_amdgcn_mfma_f32_16x16x32_bf16(aw[1], bw[no][1], acc, 0,0,0);
            #pragma unroll
            for (int j = 0; j < 4; ++j) {
                long long pr = p0 + g*4 + j;
                if (pr < N) {
                    float v = acc[j] + bias4[no];
                    if (no < 2) cv[pr*32 + no*16 + m] = v;
                    else        gl[pr*32 + (no-2)*16 + m] = v;
                }
            }
        }
    }
}

// ---- K2 fused: r1 = relu(sconv(cv,Wr1)); out1/out2 = relu(sconv(gl,Wq1/Wq2));
//      s12 = out1+out2; m1 = rowmean(out1); bsum += batch-sum(out2) ----
__global__ __launch_bounds__(1024, 4) void k2_fused(
    const float* __restrict__ cv, const float* __restrict__ gl,
    const int* __restrict__ nbr, const int* __restrict__ batch_id,
    const float* __restrict__ Wr1, const float* __restrict__ br1,
    const float* __restrict__ Wq1, const float* __restrict__ bq1,
    const float* __restrict__ Wq2, const float* __restrict__ bq2,
    float* __restrict__ r1, float* __restrict__ s12, float* __restrict__ m1,
    float* __restrict__ bsum, long long N)
{
    __shared__ u32 wr[26*512];    // Wr1 sparse, bf16x2 over c-pairs
    __shared__ u32 wq[26*1024];   // (Wq1,Wq2) packed per (c,o)
    __shared__ float lbs[128];
    stage_w26(Wr1, wr, 1024);
    for (int i = threadIdx.x; i < 26*1024; i += 1024) {
        int o = i & 31, c = (i >> 5) & 31, kp = i >> 10;
        int k = kp + (kp >= 13 ? 1 : 0);
        wq[i] = packbf(Wq1[k*1024 + c*32 + o], Wq2[k*1024 + c*32 + o]);
    }
    if (threadIdx.x < 128) lbs[threadIdx.x] = 0.f;
    __syncthreads();

    const int lane = threadIdx.x & 63, o = lane & 31, h = lane >> 5;
    const bool idxlane = (lane < 27 && lane != 13);
    // self (k=13) weights, register-packed bf16x2
    u32 wsr[8], wsq[16];
    #pragma unroll
    for (int cc2 = 0; cc2 < 8; ++cc2)
        wsr[cc2] = packbf(Wr1[13*1024 + (h*16+2*cc2)*32 + o], Wr1[13*1024 + (h*16+2*cc2+1)*32 + o]);
    #pragma unroll
    for (int cc = 0; cc < 16; ++cc)
        wsq[cc] = packbf(Wq1[13*1024 + (h*16+cc)*32 + o], Wq2[13*1024 + (h*16+cc)*32 + o]);
    const float brv = br1[o], b1 = bq1[o], b2 = bq2[o];

    const long long wave = (long long)blockIdx.x*16 + (threadIdx.x>>6);
    long long n0 = wave*CPT, n1 = n0+CPT; if (n1 > N) n1 = N;

    // pipeline state
    int cidx = -1, fidx = -1;
    u64 cmask = 0;
    float ccv0=0.f, ccv1=0.f, cgl0=0.f, cgl1=0.f, cselfc=0.f, cselfg=0.f;
    if (n0 < n1) {
        cidx = idxlane ? nbr[(long long)lane*N + n0] : -1;
        cmask = __ballot(cidx >= 0);
        cselfc = cv[n0*HC + o]; cselfg = gl[n0*HC + o];
        if (cmask) {
            int k0 = (int)__builtin_ctzll(cmask);
            int i0 = __shfl(cidx, k0, 64);
            ccv0 = cv[(long long)i0*HC + o]; cgl0 = gl[(long long)i0*HC + o];
            u64 m2 = cmask & (cmask-1);
            if (m2) {
                int k1 = (int)__builtin_ctzll(m2);
                int i1 = __shfl(cidx, k1, 64);
                ccv1 = cv[(long long)i1*HC + o]; cgl1 = gl[(long long)i1*HC + o];
            }
        }
        if (n0+1 < n1) fidx = idxlane ? nbr[(long long)lane*N + n0+1] : -1;
    }

    for (long long n = n0; n < n1; ++n) {
        // ---- prefetch point n+1 (ballot + first-2 gathers), issue idx load for n+2 ----
        int tidx = fidx;
        u64 nmask = 0;
        float ncv0=0.f, ncv1=0.f, ngl0=0.f, ngl1=0.f, nselfc=0.f, nselfg=0.f;
        if (n+1 < n1) {
            nmask = __ballot(tidx >= 0);
            nselfc = cv[(n+1)*HC + o]; nselfg = gl[(n+1)*HC + o];
            if (nmask) {
                int k0 = (int)__builtin_ctzll(nmask);
                int i0 = __shfl(tidx, k0, 64);
                ncv0 = cv[(long long)i0*HC + o]; ngl0 = gl[(long long)i0*HC + o];
                u64 m2 = nmask & (nmask-1);
                if (m2) {
                    int k1 = (int)__builtin_ctzll(m2);
                    int i1 = __shfl(tidx, k1, 64);
                    ncv1 = cv[(long long)i1*HC + o]; ngl1 = gl[(long long)i1*HC + o];
                }
            }
            if (n+2 < n1) fidx = idxlane ? nbr[(long long)lane*N + n+2] : -1;
        }
        // ---- compute point n ----
        float accr = 0.f, acc1 = 0.f, acc2 = 0.f;
        #pragma unroll
        for (int cc2 = 0; cc2 < 8; ++cc2) {
            u32 wv = wsr[cc2];
            float xv0 = __shfl(cselfc, h*16 + 2*cc2, 64);
            float xv1 = __shfl(cselfc, h*16 + 2*cc2 + 1, 64);
            accr = fmaf(u2f(wv << 16), xv0, accr);
            accr = fmaf(u2f(wv & 0xffff0000u), xv1, accr);
        }
        #pragma unroll
        for (int cc = 0; cc < 16; ++cc) {
            u32 wv = wsq[cc];
            float xv = __shfl(cselfg, h*16 + cc, 64);
            acc1 = fmaf(u2f(wv << 16), xv, acc1);
            acc2 = fmaf(u2f(wv & 0xffff0000u), xv, acc2);
        }
        u64 mm = cmask; int j = 0;
        while (mm) {
            int k = (int)__builtin_ctzll(mm); mm &= mm-1;
            float rc, rg;
            if (j == 0)      { rc = ccv0; rg = cgl0; }
            else if (j == 1) { rc = ccv1; rg = cgl1; }
            else { int ii = __shfl(cidx, k, 64);
                   rc = cv[(long long)ii*HC + o]; rg = gl[(long long)ii*HC + o]; }
            int ks = k - (k > 13 ? 1 : 0);
            const u32* wpr = wr + ks*512 + h*256 + o;
            const u32* wpq = wq + ks*1024 + h*512 + o;
            #pragma unroll
            for (int cc2 = 0; cc2 < 8; ++cc2) {
                u32 wv = wpr[cc2*32];
                float xv0 = __shfl(rc, h*16 + 2*cc2, 64);
                float xv1 = __shfl(rc, h*16 + 2*cc2 + 1, 64);
                accr = fmaf(u2f(wv << 16), xv0, accr);
                accr = fmaf(u2f(wv & 0xffff0000u), xv1, accr);
            }
            #pragma unroll
            for (int cc = 0; cc < 16; ++cc) {
                u32 wv = wpq[cc*32];
                float xv = __shfl(rg, h*16 + cc, 64);
                acc1 = fmaf(u2f(wv << 16), xv, acc1);
                acc2 = fmaf(u2f(wv & 0xffff0000u), xv, acc2);
            }
            ++j;
        }
        accr += __shfl_xor(accr, 32, 64);
        acc1 += __shfl_xor(acc1, 32, 64);
        acc2 += __shfl_xor(acc2, 32, 64);
        float rv = fmaxf(accr + brv, 0.f);
        float o1 = fmaxf(acc1 + b1, 0.f);
        float o2 = fmaxf(acc2 + b2, 0.f);
        float sm = o1;
        #pragma unroll
        for (int d = 1; d < 32; d <<= 1) sm += __shfl_xor(sm, d, 64);
        int b = batch_id[n];
        if (lane < HC) {
            r1[n*HC + o] = rv;
            s12[n*HC + o] = o1 + o2;
            atomicAdd(&lbs[b*HC + o], o2);
        }
        if (lane == 0) m1[n] = sm * (1.f/32.f);
        // rotate pipeline
        cidx = tidx; cmask = nmask;
        ccv0 = ncv0; ccv1 = ncv1; cgl0 = ngl0; cgl1 = ngl1;
        cselfc = nselfc; cselfg = nselfg;
    }
    __syncthreads();
    if (threadIdx.x < 128) atomicAdd(&bsum[threadIdx.x], lbs[threadIdx.x]);
}

// ---- K3 fused: r2-conv -> cx2 tile in LDS -> MFMA epilogue -> out ----
__global__ __launch_bounds__(512, 4) void k3_fused(
    const float* __restrict__ r1, const float* __restrict__ cv,
    const float* __restrict__ gl, const float* __restrict__ s12,
    const float* __restrict__ m1, const float* __restrict__ bsum,
    const int* __restrict__ nbr, const int* __restrict__ batch_id,
    const float* __restrict__ Wr2, const float* __restrict__ br2,
    const float* __restrict__ Wq3, const float* __restrict__ bq3,
    const float* __restrict__ Wg2, const float* __restrict__ bg2,
    const float* __restrict__ x, float* __restrict__ out,
    long long N, const int* __restrict__ bsz)
{
    __shared__ u32 wr[26*512];
    __shared__ __align__(16) u16 finL[8][16*40];
    __shared__ __align__(16) u16 a2L[8][16*72];
    stage_w26(Wr2, wr, 512);
    __syncthreads();

    const int wid = threadIdx.x >> 6;
    u16* fin_bf = finL[wid];
    u16* a2_bf  = a2L[wid];
    const int lane = threadIdx.x & 63, o = lane & 31, h = lane >> 5;
    const int m = lane & 15, g = lane >> 4;
    const bool idxlane = (lane < 27 && lane != 13);

    u32 wsr[8];
    #pragma unroll
    for (int cc2 = 0; cc2 < 8; ++cc2)
        wsr[cc2] = packbf(Wr2[13*1024 + (h*16+2*cc2)*32 + o], Wr2[13*1024 + (h*16+2*cc2+1)*32 + o]);
    const float brv = br2[o];

    const long long wave = (long long)blockIdx.x*8 + wid;
    const long long p0 = wave*CPT;
    long long n0 = p0, n1 = n0+CPT; if (n1 > N) n1 = N;

    // ---- conv phase: cx2 = relu(sconv(r1,Wr2)+br2) + 2*cv -> a2 tile (bf16) ----
    int cidx = -1, fidx = -1;
    u64 cmask = 0;
    float cr0=0.f, cr1v=0.f, cself=0.f, ccv=0.f;
    if (n0 < n1) {
        cidx = idxlane ? nbr[(long long)lane*N + n0] : -1;
        cmask = __ballot(cidx >= 0);
        cself = r1[n0*HC + o]; ccv = cv[n0*HC + o];
        if (cmask) {
            int k0 = (int)__builtin_ctzll(cmask);
            int i0 = __shfl(cidx, k0, 64);
            cr0 = r1[(long long)i0*HC + o];
            u64 m2 = cmask & (cmask-1);
            if (m2) {
                int k1 = (int)__builtin_ctzll(m2);
                int i1 = __shfl(cidx, k1, 64);
                cr1v = r1[(long long)i1*HC + o];
            }
        }
        if (n0+1 < n1) fidx = idxlane ? nbr[(long long)lane*N + n0+1] : -1;
    }
    for (long long n = n0; n < n1; ++n) {
        int tidx = fidx;
        u64 nmask = 0;
        float nr0=0.f, nr1=0.f, nself=0.f, ncv=0.f;
        if (n+1 < n1) {
            nmask = __ballot(tidx >= 0);
            nself = r1[(n+1)*HC + o]; ncv = cv[(n+1)*HC + o];
            if (nmask) {
                int k0 = (int)__builtin_ctzll(nmask);
                int i0 = __shfl(tidx, k0, 64);
                nr0 = r1[(long long)i0*HC + o];
                u64 m2 = nmask & (nmask-1);
                if (m2) {
                    int k1 = (int)__builtin_ctzll(m2);
                    int i1 = __shfl(tidx, k1, 64);
                    nr1 = r1[(long long)i1*HC + o];
                }
            }
            if (n+2 < n1) fidx = idxlane ? nbr[(long long)lane*N + n+2] : -1;
        }
        float acc = 0.f;
        #pragma unroll
        for (int cc2 = 0; cc2 < 8; ++cc2) {
            u32 wv = wsr[cc2];
            float xv0 = __shfl(cself, h*16 + 2*cc2, 64);
            float xv1 = __shfl(cself, h*16 + 2*cc2 + 1, 64);
            acc = fmaf(u2f(wv << 16), xv0, acc);
            acc = fmaf(u2f(wv & 0xffff0000u), xv1, acc);
        }
        u64 mm = cmask; int j = 0;
        while (mm) {
            int k = (int)__builtin_ctzll(mm); mm &= mm-1;
            float rr;
            if (j == 0)      rr = cr0;
            else if (j == 1) rr = cr1v;
            else { int ii = __shfl(cidx, k, 64); rr = r1[(long long)ii*HC + o]; }
            int ks = k - (k > 13 ? 1 : 0);
            const u32* wpr = wr + ks*512 + h*256 + o;
            #pragma unroll
            for (int cc2 = 0; cc2 < 8; ++cc2) {
                u32 wv = wpr[cc2*32];
                float xv0 = __shfl(rr, h*16 + 2*cc2, 64);
                float xv1 = __shfl(rr, h*16 + 2*cc2 + 1, 64);
                acc = fmaf(u2f(wv << 16), xv0, acc);
                acc = fmaf(u2f(wv & 0xffff0000u), xv1, acc);
            }
            ++j;
        }
        acc += __shfl_xor(acc, 32, 64);
        float cx2 = fmaxf(acc + brv, 0.f) + 2.f*ccv;
        if (lane < HC) a2_bf[(int)(n - p0)*72 + o] = f2bf(cx2);
        cidx = tidx; cmask = nmask;
        cr0 = nr0; cr1v = nr1; cself = nself; ccv = ncv;
    }
    if (p0 >= N) return;

    // ---- epilogue (MFMA), round-5 proven structure ----
    bf16x8 bq[2];
    #pragma unroll
    for (int no = 0; no < 2; ++no)
      #pragma unroll
      for (int j = 0; j < 8; ++j)
        bq[no][j] = bfs(Wq3[(g*8+j)*32 + no*16 + m]);
    bf16x8 bgw[4][2];
    #pragma unroll
    for (int no = 0; no < 4; ++no)
      #pragma unroll
      for (int kf = 0; kf < 2; ++kf)
        #pragma unroll
        for (int j = 0; j < 8; ++j)
          bgw[no][kf][j] = bfs(Wg2[(kf*32 + g*8 + j)*64 + no*16 + m]);
    const float bq3a = bq3[m], bq3b = bq3[16+m];
    float bgb[4];
    #pragma unroll
    for (int no = 0; no < 4; ++no) bgb[no] = bg2[no*16 + m];
    const float invNP = (float)(*bsz) / (float)N;
    const int p_lin = lane >> 2, c0 = (lane & 3) * 8;

    // phase A: fin = sqrt(m1*m2) + s12 -> LDS (bf16)
    {
        long long pp = p0 + p_lin; if (pp > N-1) pp = N-1;
        float m1v = m1[pp];
        int b = batch_id[pp];
        const float4* bsp = (const float4*)(bsum + b*32 + c0);
        float4 bs0 = bsp[0], bs1 = bsp[1];
        const float4* s12p = (const float4*)(s12 + pp*32 + c0);
        float4 s0 = s12p[0], s1 = s12p[1];
        float bsv[8] = {bs0.x,bs0.y,bs0.z,bs0.w,bs1.x,bs1.y,bs1.z,bs1.w};
        float sv[8]  = {s0.x,s0.y,s0.z,s0.w,s1.x,s1.y,s1.z,s1.w};
        bf16x8 fbv;
        #pragma unroll
        for (int j = 0; j < 8; ++j) {
            float enc = sqrtf(m1v * bsv[j] * invNP + 1e-12f);
            fbv[j] = bfs(enc + sv[j]);
        }
        *(bf16x8*)&fin_bf[p_lin*40 + c0] = fbv;
    }
    asm volatile("s_waitcnt lgkmcnt(0)" ::: "memory");
    // phase B: f = fin @ Wq3
    bf16x8 af = *(const bf16x8*)&fin_bf[m*40 + g*8];
    f32x4 f0 = {0.f,0.f,0.f,0.f}, f1 = {0.f,0.f,0.f,0.f};
    f0 = __builtin_amdgcn_mfma_f32_16x16x32_bf16(af, bq[0], f0, 0,0,0);
    f1 = __builtin_amdgcn_mfma_f32_16x16x32_bf16(af, bq[1], f1, 0,0,0);
    // phase C: glo = relu(gl - relu(f+bq3)) -> a2 cols 32..63
    #pragma unroll
    for (int j = 0; j < 4; ++j) {
        int row = g*4 + j;
        long long pr = p0 + row; if (pr > N-1) pr = N-1;
        float fa = fmaxf(f0[j] + bq3a, 0.f);
        float fb = fmaxf(f1[j] + bq3b, 0.f);
        float g0 = fmaxf(gl[pr*32 + m] - fa, 0.f);
        float g1 = fmaxf(gl[pr*32 + 16 + m] - fb, 0.f);
        a2_bf[row*72 + 32 + m] = f2bf(g0);
        a2_bf[row*72 + 48 + m] = f2bf(g1);
    }
    asm volatile("s_waitcnt lgkmcnt(0)" ::: "memory");
    // phase D: out = x + [cx2|glo] @ Wg2 + bg2
    bf16x8 a20 = *(const bf16x8*)&a2_bf[m*72 + g*8];
    bf16x8 a21 = *(const bf16x8*)&a2_bf[m*72 + 32 + g*8];
    #pragma unroll
    for (int no = 0; no < 4; ++no) {
        f32x4 acc = {0.f,0.f,0.f,0.f};
        acc = __builtin_amdgcn_mfma_f32_16x16x32_bf16(a20, bgw[no][0], acc, 0,0,0);
        acc = __builtin_amdgcn_mfma_f32_16x16x32_bf16(a21, bgw[no][1], acc, 0,0,0);
        #pragma unroll
        for (int j = 0; j < 4; ++j) {
            long long pr = p0 + g*4 + j;
            if (pr < N)
                out[pr*64 + no*16 + m] = x[pr*64 + no*16 + m] + acc[j] + bgb[no];
        }
    }
}

extern "C" void kernel_launch(void* const* d_in, const int* in_sizes, int n_in,
                              void* d_out, int out_size, void* d_ws, size_t ws_size,
                              hipStream_t stream) {
    const float* x   = (const float*)d_in[0];
    const float* Wg1 = (const float*)d_in[1];
    const float* bg1 = (const float*)d_in[2];
    const float* Wg2 = (const float*)d_in[3];
    const float* bg2 = (const float*)d_in[4];
    const float* Wr1 = (const float*)d_in[5];
    const float* br1 = (const float*)d_in[6];
    const float* Wr2 = (const float*)d_in[7];
    const float* br2 = (const float*)d_in[8];
    const float* Wq1 = (const float*)d_in[9];
    const float* bq1 = (const float*)d_in[10];
    const float* Wq2 = (const float*)d_in[11];
    const float* bq2 = (const float*)d_in[12];
    const float* Wq3 = (const float*)d_in[13];
    const float* bq3 = (const float*)d_in[14];
    const int* nbr   = (const int*)d_in[15];
    const int* bid   = (const int*)d_in[16];
    const int* bsz   = (const int*)d_in[17];

    const long long N = (long long)in_sizes[0] / 64;

    float* cv   = (float*)d_ws;
    float* gl   = cv  + N * 32;
    float* r1   = gl  + N * 32;
    float* s12  = r1  + N * 32;
    float* m1   = s12 + N * 32;
    float* bsum = m1  + N;               // 128 floats used

    float* out = (float*)d_out;

    hipMemsetAsync(bsum, 0, 128 * sizeof(float), stream);

    long long tiles = (N + 15) / 16;
    long long gwaves = (tiles + 3) / 4;
    int gblocks = (int)((gwaves + 3) / 4);
    k1_mfma<<<gblocks, 256, 0, stream>>>(x, Wg1, bg1, cv, gl, N);

    long long cwaves = (N + CPT - 1) / CPT;
    int blk16 = (int)((cwaves + 15) / 16);
    int blk8  = (int)((cwaves + 7) / 8);
    k2_fused<<<blk16, 1024, 0, stream>>>(cv, gl, nbr, bid, Wr1, br1, Wq1, bq1, Wq2, bq2,
                                         r1, s12, m1, bsum, N);
    k3_fused<<<blk8, 512, 0, stream>>>(r1, cv, gl, s12, m1, bsum, nbr, bid,
                                       Wr2, br2, Wq3, bq3, Wg2, bg2, x, out, N, bsz);
}

// Round 7
// 671.314 us; speedup vs baseline: 1.3543x; 1.3543x over previous
//
#include <hip/hip_runtime.h>
#include <stdint.h>

typedef unsigned int u32;
typedef unsigned short u16;
typedef unsigned long long u64;
typedef __attribute__((ext_vector_type(8))) short bf16x8;
typedef __attribute__((ext_vector_type(4))) float f32x4;

#define HC 32
#define CPT 16   // points per wave in conv kernels

__device__ __forceinline__ float u2f(u32 u){ union{u32 i;float f;}v; v.i=u; return v.f; }
__device__ __forceinline__ u16 f2bf(float f){ union{float f;u32 i;}v; v.f=f; u32 i=v.i;
    return (u16)((i + 0x7FFFu + ((i>>16)&1u))>>16); }  // RNE
__device__ __forceinline__ short bfs(float f){ return (short)f2bf(f); }
__device__ __forceinline__ u32 packbf(float a, float b){ return (u32)f2bf(a) | ((u32)f2bf(b)<<16); }

// stage 26 sparse k-slices (skip k=13) of one 27x32x32 matrix, bf16x2 c-pairs
__device__ __forceinline__ void stage_w26(const float* __restrict__ W, u32* __restrict__ wl, int nthr) {
    for (int i = threadIdx.x; i < 26*512; i += nthr) {
        int o = i & 31, row = (i >> 5) & 15, kp = i >> 9;
        int k = kp + (kp >= 13 ? 1 : 0);
        int c0 = (row >> 3)*16 + (row & 7)*2;
        wl[i] = packbf(W[k*1024 + c0*32 + o], W[k*1024 + (c0+1)*32 + o]);
    }
}

// ---- K1: y = x @ Wg1 + bg1 -> cv | gl  (MFMA) ----
__global__ __launch_bounds__(256) void k1_mfma(
    const float* __restrict__ x, const float* __restrict__ Wg1, const float* __restrict__ bg1,
    float* __restrict__ cv, float* __restrict__ gl, long long N)
{
    const int lane = threadIdx.x & 63;
    const int m = lane & 15, g = lane >> 4;
    bf16x8 bw[4][2];
    #pragma unroll
    for (int no = 0; no < 4; ++no)
      #pragma unroll
      for (int kf = 0; kf < 2; ++kf)
        #pragma unroll
        for (int j = 0; j < 8; ++j)
            bw[no][kf][j] = bfs(Wg1[(kf*32 + g*8 + j)*64 + no*16 + m]);
    float bias4[4];
    #pragma unroll
    for (int no = 0; no < 4; ++no) bias4[no] = bg1[no*16 + m];

    const long long wave = (long long)blockIdx.x*4 + (threadIdx.x>>6);
    long long t0 = wave * 4;
    #pragma unroll 1
    for (long long t = t0; t < t0+4; ++t) {
        long long p0 = t*16;
        if (p0 >= N) break;
        long long pr_a = p0 + m; if (pr_a > N-1) pr_a = N-1;
        const float4* xr = (const float4*)(x + pr_a*64);
        bf16x8 aw[2];
        #pragma unroll
        for (int kf = 0; kf < 2; ++kf) {
            float4 lo = xr[kf*8 + g*2];
            float4 hi = xr[kf*8 + g*2 + 1];
            aw[kf][0]=bfs(lo.x); aw[kf][1]=bfs(lo.y); aw[kf][2]=bfs(lo.z); aw[kf][3]=bfs(lo.w);
            aw[kf][4]=bfs(hi.x); aw[kf][5]=bfs(hi.y); aw[kf][6]=bfs(hi.z); aw[kf][7]=bfs(hi.w);
        }
        #pragma unroll
        for (int no = 0; no < 4; ++no) {
            f32x4 acc = {0.f,0.f,0.f,0.f};
            acc = __builtin_amdgcn_mfma_f32_16x16x32_bf16(aw[0], bw[no][0], acc, 0,0,0);
            acc = __builtin_amdgcn_mfma_f32_16x16x32_bf16(aw[1], bw[no][1], acc, 0,0,0);
            #pragma unroll
            for (int j = 0; j < 4; ++j) {
                long long pr = p0 + g*4 + j;
                if (pr < N) {
                    float v = acc[j] + bias4[no];
                    if (no < 2) cv[pr*32 + no*16 + m] = v;
                    else        gl[pr*32 + (no-2)*16 + m] = v;
                }
            }
        }
    }
}

// ---- K2 fused (minimal live state): r1 / s12 / m1 / bsum in one pass ----
__global__ __launch_bounds__(1024, 4) void k2_fused(
    const float* __restrict__ cv, const float* __restrict__ gl,
    const int* __restrict__ nbr, const int* __restrict__ batch_id,
    const float* __restrict__ Wr1, const float* __restrict__ br1,
    const float* __restrict__ Wq1, const float* __restrict__ bq1,
    const float* __restrict__ Wq2, const float* __restrict__ bq2,
    float* __restrict__ r1, float* __restrict__ s12, float* __restrict__ m1,
    float* __restrict__ bsum, long long N)
{
    __shared__ u32 wr[26*512];    // Wr1 sparse, bf16x2 over c-pairs
    __shared__ u32 wq[26*1024];   // (Wq1,Wq2) packed per (c,o)
    __shared__ float lbs[128];
    stage_w26(Wr1, wr, 1024);
    for (int i = threadIdx.x; i < 26*1024; i += 1024) {
        int o = i & 31, c = (i >> 5) & 31, kp = i >> 10;
        int k = kp + (kp >= 13 ? 1 : 0);
        wq[i] = packbf(Wq1[k*1024 + c*32 + o], Wq2[k*1024 + c*32 + o]);
    }
    if (threadIdx.x < 128) lbs[threadIdx.x] = 0.f;
    __syncthreads();

    const int lane = threadIdx.x & 63, o = lane & 31, h = lane >> 5;
    const bool idxlane = (lane < 27 && lane != 13);
    // self (k=13) weights, register-packed bf16x2
    u32 wsr[8], wsq[16];
    #pragma unroll
    for (int cc2 = 0; cc2 < 8; ++cc2)
        wsr[cc2] = packbf(Wr1[13*1024 + (h*16+2*cc2)*32 + o], Wr1[13*1024 + (h*16+2*cc2+1)*32 + o]);
    #pragma unroll
    for (int cc = 0; cc < 16; ++cc)
        wsq[cc] = packbf(Wq1[13*1024 + (h*16+cc)*32 + o], Wq2[13*1024 + (h*16+cc)*32 + o]);
    const float brv = br1[o], b1 = bq1[o], b2 = bq2[o];

    const long long wave = (long long)blockIdx.x*16 + (threadIdx.x>>6);
    long long n0 = wave*CPT, n1 = n0+CPT; if (n1 > N) n1 = N;

    // cross-iter prefetch: only next idx + next self rows (3 VGPRs)
    int cidx = -1; float pselfc = 0.f, pselfg = 0.f;
    if (n0 < n1) {
        cidx = idxlane ? nbr[(long long)lane*N + n0] : -1;
        pselfc = cv[n0*HC + o]; pselfg = gl[n0*HC + o];
    }

    for (long long n = n0; n < n1; ++n) {
        int idxv = cidx;
        float selfc = pselfc, selfg = pselfg;
        u64 mask = __ballot(idxv >= 0);
        // issue first-2 gathers now; hide their latency under self-MACs
        float rc0=0.f, rg0=0.f, rc1=0.f, rg1=0.f;
        u64 m2 = 0;
        if (mask) {
            int k0 = (int)__builtin_ctzll(mask);
            int i0 = __shfl(idxv, k0, 64);
            const float* pc = cv + (long long)i0*HC;
            const float* pg = gl + (long long)i0*HC;
            rc0 = pc[o]; rg0 = pg[o];
            m2 = mask & (mask-1);
            if (m2) {
                int k1 = (int)__builtin_ctzll(m2);
                int i1 = __shfl(idxv, k1, 64);
                rc1 = cv[(long long)i1*HC + o]; rg1 = gl[(long long)i1*HC + o];
            }
        }
        // prefetch next-iteration state
        if (n+1 < n1) {
            cidx = idxlane ? nbr[(long long)lane*N + n+1] : -1;
            pselfc = cv[(n+1)*HC + o]; pselfg = gl[(n+1)*HC + o];
        }
        // self MACs
        float accr = 0.f, acc1 = 0.f, acc2 = 0.f;
        #pragma unroll
        for (int cc2 = 0; cc2 < 8; ++cc2) {
            u32 wv = wsr[cc2];
            float xv0 = __shfl(selfc, h*16 + 2*cc2, 64);
            float xv1 = __shfl(selfc, h*16 + 2*cc2 + 1, 64);
            accr = fmaf(u2f(wv << 16), xv0, accr);
            accr = fmaf(u2f(wv & 0xffff0000u), xv1, accr);
        }
        #pragma unroll
        for (int cc = 0; cc < 16; ++cc) {
            u32 wv = wsq[cc];
            float xv = __shfl(selfg, h*16 + cc, 64);
            acc1 = fmaf(u2f(wv << 16), xv, acc1);
            acc2 = fmaf(u2f(wv & 0xffff0000u), xv, acc2);
        }
        // sparse neighbors
        u64 mm = mask; int j = 0;
        while (mm) {
            int k = (int)__builtin_ctzll(mm); mm &= mm-1;
            float rc, rg;
            if (j == 0)      { rc = rc0; rg = rg0; }
            else if (j == 1) { rc = rc1; rg = rg1; }
            else { int ii = __shfl(idxv, k, 64);
                   rc = cv[(long long)ii*HC + o]; rg = gl[(long long)ii*HC + o]; }
            int ks = k - (k > 13 ? 1 : 0);
            const u32* wpr = wr + ks*512 + h*256 + o;
            const u32* wpq = wq + ks*1024 + h*512 + o;
            #pragma unroll
            for (int cc2 = 0; cc2 < 8; ++cc2) {
                u32 wv = wpr[cc2*32];
                float xv0 = __shfl(rc, h*16 + 2*cc2, 64);
                float xv1 = __shfl(rc, h*16 + 2*cc2 + 1, 64);
                accr = fmaf(u2f(wv << 16), xv0, accr);
                accr = fmaf(u2f(wv & 0xffff0000u), xv1, accr);
            }
            #pragma unroll
            for (int cc = 0; cc < 16; ++cc) {
                u32 wv = wpq[cc*32];
                float xv = __shfl(rg, h*16 + cc, 64);
                acc1 = fmaf(u2f(wv << 16), xv, acc1);
                acc2 = fmaf(u2f(wv & 0xffff0000u), xv, acc2);
            }
            ++j;
        }
        accr += __shfl_xor(accr, 32, 64);
        acc1 += __shfl_xor(acc1, 32, 64);
        acc2 += __shfl_xor(acc2, 32, 64);
        float rv = fmaxf(accr + brv, 0.f);
        float o1 = fmaxf(acc1 + b1, 0.f);
        float o2 = fmaxf(acc2 + b2, 0.f);
        float sm = o1;
        #pragma unroll
        for (int d = 1; d < 32; d <<= 1) sm += __shfl_xor(sm, d, 64);
        int b = batch_id[n];
        if (lane < HC) {
            r1[n*HC + o] = rv;
            s12[n*HC + o] = o1 + o2;
            atomicAdd(&lbs[b*HC + o], o2);
        }
        if (lane == 0) m1[n] = sm * (1.f/32.f);
    }
    __syncthreads();
    if (threadIdx.x < 128) atomicAdd(&bsum[threadIdx.x], lbs[threadIdx.x]);
}

// ---- K3 fused: r2-conv -> cx2 tile in LDS -> MFMA epilogue -> out ----
__global__ __launch_bounds__(512, 4) void k3_fused(
    const float* __restrict__ r1, const float* __restrict__ cv,
    const float* __restrict__ gl, const float* __restrict__ s12,
    const float* __restrict__ m1, const float* __restrict__ bsum,
    const int* __restrict__ nbr, const int* __restrict__ batch_id,
    const float* __restrict__ Wr2, const float* __restrict__ br2,
    const float* __restrict__ Wq3, const float* __restrict__ bq3,
    const float* __restrict__ Wg2, const float* __restrict__ bg2,
    const float* __restrict__ x, float* __restrict__ out,
    long long N, const int* __restrict__ bsz)
{
    __shared__ u32 wr[26*512];
    __shared__ __align__(16) u16 finL[8][16*40];
    __shared__ __align__(16) u16 a2L[8][16*72];
    stage_w26(Wr2, wr, 512);
    __syncthreads();

    const int wid = threadIdx.x >> 6;
    u16* fin_bf = finL[wid];
    u16* a2_bf  = a2L[wid];
    const int lane = threadIdx.x & 63, o = lane & 31, h = lane >> 5;
    const int m = lane & 15, g = lane >> 4;
    const bool idxlane = (lane < 27 && lane != 13);

    u32 wsr[8];
    #pragma unroll
    for (int cc2 = 0; cc2 < 8; ++cc2)
        wsr[cc2] = packbf(Wr2[13*1024 + (h*16+2*cc2)*32 + o], Wr2[13*1024 + (h*16+2*cc2+1)*32 + o]);
    const float brv = br2[o];

    const long long wave = (long long)blockIdx.x*8 + wid;
    const long long p0 = wave*CPT;
    long long n0 = p0, n1 = n0+CPT; if (n1 > N) n1 = N;

    // conv phase: cx2 = relu(sconv(r1,Wr2)+br2) + 2*cv -> a2 tile (bf16)
    int cidx = -1; float pself = 0.f, pcv = 0.f;
    if (n0 < n1) {
        cidx = idxlane ? nbr[(long long)lane*N + n0] : -1;
        pself = r1[n0*HC + o]; pcv = cv[n0*HC + o];
    }
    for (long long n = n0; n < n1; ++n) {
        int idxv = cidx;
        float selfv = pself, cvv = pcv;
        u64 mask = __ballot(idxv >= 0);
        float rr0=0.f, rr1=0.f;
        u64 m2 = 0;
        if (mask) {
            int k0 = (int)__builtin_ctzll(mask);
            int i0 = __shfl(idxv, k0, 64);
            rr0 = r1[(long long)i0*HC + o];
            m2 = mask & (mask-1);
            if (m2) {
                int k1 = (int)__builtin_ctzll(m2);
                int i1 = __shfl(idxv, k1, 64);
                rr1 = r1[(long long)i1*HC + o];
            }
        }
        if (n+1 < n1) {
            cidx = idxlane ? nbr[(long long)lane*N + n+1] : -1;
            pself = r1[(n+1)*HC + o]; pcv = cv[(n+1)*HC + o];
        }
        float acc = 0.f;
        #pragma unroll
        for (int cc2 = 0; cc2 < 8; ++cc2) {
            u32 wv = wsr[cc2];
            float xv0 = __shfl(selfv, h*16 + 2*cc2, 64);
            float xv1 = __shfl(selfv, h*16 + 2*cc2 + 1, 64);
            acc = fmaf(u2f(wv << 16), xv0, acc);
            acc = fmaf(u2f(wv & 0xffff0000u), xv1, acc);
        }
        u64 mm = mask; int j = 0;
        while (mm) {
            int k = (int)__builtin_ctzll(mm); mm &= mm-1;
            float rr;
            if (j == 0)      rr = rr0;
            else if (j == 1) rr = rr1;
            else { int ii = __shfl(idxv, k, 64); rr = r1[(long long)ii*HC + o]; }
            int ks = k - (k > 13 ? 1 : 0);
            const u32* wpr = wr + ks*512 + h*256 + o;
            #pragma unroll
            for (int cc2 = 0; cc2 < 8; ++cc2) {
                u32 wv = wpr[cc2*32];
                float xv0 = __shfl(rr, h*16 + 2*cc2, 64);
                float xv1 = __shfl(rr, h*16 + 2*cc2 + 1, 64);
                acc = fmaf(u2f(wv << 16), xv0, acc);
                acc = fmaf(u2f(wv & 0xffff0000u), xv1, acc);
            }
            ++j;
        }
        acc += __shfl_xor(acc, 32, 64);
        float cx2 = fmaxf(acc + brv, 0.f) + 2.f*cvv;
        if (lane < HC) a2_bf[(int)(n - p0)*72 + o] = f2bf(cx2);
    }
    if (p0 >= N) return;

    // epilogue (MFMA)
    bf16x8 bq[2];
    #pragma unroll
    for (int no = 0; no < 2; ++no)
      #pragma unroll
      for (int j = 0; j < 8; ++j)
        bq[no][j] = bfs(Wq3[(g*8+j)*32 + no*16 + m]);
    bf16x8 bgw[4][2];
    #pragma unroll
    for (int no = 0; no < 4; ++no)
      #pragma unroll
      for (int kf = 0; kf < 2; ++kf)
        #pragma unroll
        for (int j = 0; j < 8; ++j)
          bgw[no][kf][j] = bfs(Wg2[(kf*32 + g*8 + j)*64 + no*16 + m]);
    const float bq3a = bq3[m], bq3b = bq3[16+m];
    float bgb[4];
    #pragma unroll
    for (int no = 0; no < 4; ++no) bgb[no] = bg2[no*16 + m];
    const float invNP = (float)(*bsz) / (float)N;
    const int p_lin = lane >> 2, c0 = (lane & 3) * 8;

    {
        long long pp = p0 + p_lin; if (pp > N-1) pp = N-1;
        float m1v = m1[pp];
        int b = batch_id[pp];
        const float4* bsp = (const float4*)(bsum + b*32 + c0);
        float4 bs0 = bsp[0], bs1 = bsp[1];
        const float4* s12p = (const float4*)(s12 + pp*32 + c0);
        float4 s0 = s12p[0], s1 = s12p[1];
        float bsv[8] = {bs0.x,bs0.y,bs0.z,bs0.w,bs1.x,bs1.y,bs1.z,bs1.w};
        float sv[8]  = {s0.x,s0.y,s0.z,s0.w,s1.x,s1.y,s1.z,s1.w};
        bf16x8 fbv;
        #pragma unroll
        for (int j = 0; j < 8; ++j) {
            float enc = sqrtf(m1v * bsv[j] * invNP + 1e-12f);
            fbv[j] = bfs(enc + sv[j]);
        }
        *(bf16x8*)&fin_bf[p_lin*40 + c0] = fbv;
    }
    asm volatile("s_waitcnt lgkmcnt(0)" ::: "memory");
    bf16x8 af = *(const bf16x8*)&fin_bf[m*40 + g*8];
    f32x4 f0 = {0.f,0.f,0.f,0.f}, f1 = {0.f,0.f,0.f,0.f};
    f0 = __builtin_amdgcn_mfma_f32_16x16x32_bf16(af, bq[0], f0, 0,0,0);
    f1 = __builtin_amdgcn_mfma_f32_16x16x32_bf16(af, bq[1], f1, 0,0,0);
    #pragma unroll
    for (int j = 0; j < 4; ++j) {
        int row = g*4 + j;
        long long pr = p0 + row; if (pr > N-1) pr = N-1;
        float fa = fmaxf(f0[j] + bq3a, 0.f);
        float fb = fmaxf(f1[j] + bq3b, 0.f);
        float g0 = fmaxf(gl[pr*32 + m] - fa, 0.f);
        float g1 = fmaxf(gl[pr*32 + 16 + m] - fb, 0.f);
        a2_bf[row*72 + 32 + m] = f2bf(g0);
        a2_bf[row*72 + 48 + m] = f2bf(g1);
    }
    asm volatile("s_waitcnt lgkmcnt(0)" ::: "memory");
    bf16x8 a20 = *(const bf16x8*)&a2_bf[m*72 + g*8];
    bf16x8 a21 = *(const bf16x8*)&a2_bf[m*72 + 32 + g*8];
    #pragma unroll
    for (int no = 0; no < 4; ++no) {
        f32x4 acc = {0.f,0.f,0.f,0.f};
        acc = __builtin_amdgcn_mfma_f32_16x16x32_bf16(a20, bgw[no][0], acc, 0,0,0);
        acc = __builtin_amdgcn_mfma_f32_16x16x32_bf16(a21, bgw[no][1], acc, 0,0,0);
        #pragma unroll
        for (int j = 0; j < 4; ++j) {
            long long pr = p0 + g*4 + j;
            if (pr < N)
                out[pr*64 + no*16 + m] = x[pr*64 + no*16 + m] + acc[j] + bgb[no];
        }
    }
}

extern "C" void kernel_launch(void* const* d_in, const int* in_sizes, int n_in,
                              void* d_out, int out_size, void* d_ws, size_t ws_size,
                              hipStream_t stream) {
    const float* x   = (const float*)d_in[0];
    const float* Wg1 = (const float*)d_in[1];
    const float* bg1 = (const float*)d_in[2];
    const float* Wg2 = (const float*)d_in[3];
    const float* bg2 = (const float*)d_in[4];
    const float* Wr1 = (const float*)d_in[5];
    const float* br1 = (const float*)d_in[6];
    const float* Wr2 = (const float*)d_in[7];
    const float* br2 = (const float*)d_in[8];
    const float* Wq1 = (const float*)d_in[9];
    const float* bq1 = (const float*)d_in[10];
    const float* Wq2 = (const float*)d_in[11];
    const float* bq2 = (const float*)d_in[12];
    const float* Wq3 = (const float*)d_in[13];
    const float* bq3 = (const float*)d_in[14];
    const int* nbr   = (const int*)d_in[15];
    const int* bid   = (const int*)d_in[16];
    const int* bsz   = (const int*)d_in[17];

    const long long N = (long long)in_sizes[0] / 64;

    float* cv   = (float*)d_ws;
    float* gl   = cv  + N * 32;
    float* r1   = gl  + N * 32;
    float* s12  = r1  + N * 32;
    float* m1   = s12 + N * 32;
    float* bsum = m1  + N;               // 128 floats used

    float* out = (float*)d_out;

    hipMemsetAsync(bsum, 0, 128 * sizeof(float), stream);

    long long tiles = (N + 15) / 16;
    long long gwaves = (tiles + 3) / 4;
    int gblocks = (int)((gwaves + 3) / 4);
    k1_mfma<<<gblocks, 256, 0, stream>>>(x, Wg1, bg1, cv, gl, N);

    long long cwaves = (N + CPT - 1) / CPT;
    int blk16 = (int)((cwaves + 15) / 16);
    int blk8  = (int)((cwaves + 7) / 8);
    k2_fused<<<blk16, 1024, 0, stream>>>(cv, gl, nbr, bid, Wr1, br1, Wq1, bq1, Wq2, bq2,
                                         r1, s12, m1, bsum, N);
    k3_fused<<<blk8, 512, 0, stream>>>(r1, cv, gl, s12, m1, bsum, nbr, bid,
                                       Wr2, br2, Wq3, bq3, Wg2, bg2, x, out, N, bsz);
}

// Round 8
// 647.572 us; speedup vs baseline: 1.4040x; 1.0367x over previous
//
#include <hip/hip_runtime.h>
#include <stdint.h>

typedef unsigned int u32;
typedef unsigned short u16;
typedef unsigned long long u64;
typedef __attribute__((ext_vector_type(8))) short bf16x8;
typedef __attribute__((ext_vector_type(4))) float f32x4;

#define HC 32
#define CPT 16   // points per wave in conv kernels

__device__ __forceinline__ float u2f(u32 u){ union{u32 i;float f;}v; v.i=u; return v.f; }
__device__ __forceinline__ u16 f2bf(float f){ union{float f;u32 i;}v; v.f=f; u32 i=v.i;
    return (u16)((i + 0x7FFFu + ((i>>16)&1u))>>16); }  // RNE
__device__ __forceinline__ short bfs(float f){ return (short)f2bf(f); }
__device__ __forceinline__ u32 packbf(float a, float b){ return (u32)f2bf(a) | ((u32)f2bf(b)<<16); }

// stage 26 sparse k-slices (skip k=13) of one 27x32x32 matrix, bf16x2 c-pairs
__device__ __forceinline__ void stage_w26(const float* __restrict__ W, u32* __restrict__ wl, int nthr) {
    for (int i = threadIdx.x; i < 26*512; i += nthr) {
        int o = i & 31, row = (i >> 5) & 15, kp = i >> 9;
        int k = kp + (kp >= 13 ? 1 : 0);
        int c0 = (row >> 3)*16 + (row & 7)*2;
        wl[i] = packbf(W[k*1024 + c0*32 + o], W[k*1024 + (c0+1)*32 + o]);
    }
}

// ---- K1: y = x @ Wg1 + bg1 -> cv | gl  (MFMA) ----
__global__ __launch_bounds__(256) void k1_mfma(
    const float* __restrict__ x, const float* __restrict__ Wg1, const float* __restrict__ bg1,
    float* __restrict__ cv, float* __restrict__ gl, long long N)
{
    const int lane = threadIdx.x & 63;
    const int m = lane & 15, g = lane >> 4;
    bf16x8 bw[4][2];
    #pragma unroll
    for (int no = 0; no < 4; ++no)
      #pragma unroll
      for (int kf = 0; kf < 2; ++kf)
        #pragma unroll
        for (int j = 0; j < 8; ++j)
            bw[no][kf][j] = bfs(Wg1[(kf*32 + g*8 + j)*64 + no*16 + m]);
    float bias4[4];
    #pragma unroll
    for (int no = 0; no < 4; ++no) bias4[no] = bg1[no*16 + m];

    const long long wave = (long long)blockIdx.x*4 + (threadIdx.x>>6);
    long long t0 = wave * 4;
    #pragma unroll 1
    for (long long t = t0; t < t0+4; ++t) {
        long long p0 = t*16;
        if (p0 >= N) break;
        long long pr_a = p0 + m; if (pr_a > N-1) pr_a = N-1;
        const float4* xr = (const float4*)(x + pr_a*64);
        bf16x8 aw[2];
        #pragma unroll
        for (int kf = 0; kf < 2; ++kf) {
            float4 lo = xr[kf*8 + g*2];
            float4 hi = xr[kf*8 + g*2 + 1];
            aw[kf][0]=bfs(lo.x); aw[kf][1]=bfs(lo.y); aw[kf][2]=bfs(lo.z); aw[kf][3]=bfs(lo.w);
            aw[kf][4]=bfs(hi.x); aw[kf][5]=bfs(hi.y); aw[kf][6]=bfs(hi.z); aw[kf][7]=bfs(hi.w);
        }
        #pragma unroll
        for (int no = 0; no < 4; ++no) {
            f32x4 acc = {0.f,0.f,0.f,0.f};
            acc = __builtin_amdgcn_mfma_f32_16x16x32_bf16(aw[0], bw[no][0], acc, 0,0,0);
            acc = __builtin_amdgcn_mfma_f32_16x16x32_bf16(aw[1], bw[no][1], acc, 0,0,0);
            #pragma unroll
            for (int j = 0; j < 4; ++j) {
                long long pr = p0 + g*4 + j;
                if (pr < N) {
                    float v = acc[j] + bias4[no];
                    if (no < 2) cv[pr*32 + no*16 + m] = v;
                    else        gl[pr*32 + (no-2)*16 + m] = v;
                }
            }
        }
    }
}

// ---- K2 fused: r1 / s12 / m1 / bsum in one pass ----
__global__ __launch_bounds__(1024, 1) void k2_fused(
    const float* __restrict__ cv, const float* __restrict__ gl,
    const int* __restrict__ nbr, const int* __restrict__ batch_id,
    const float* __restrict__ Wr1, const float* __restrict__ br1,
    const float* __restrict__ Wq1, const float* __restrict__ bq1,
    const float* __restrict__ Wq2, const float* __restrict__ bq2,
    float* __restrict__ r1, float* __restrict__ s12, float* __restrict__ m1,
    float* __restrict__ bsum, long long N)
{
    __shared__ u32 wr[26*512];    // Wr1 sparse, bf16x2 over c-pairs
    __shared__ u32 wq[26*1024];   // (Wq1,Wq2) packed per (c,o)
    __shared__ float lbs[128];
    stage_w26(Wr1, wr, 1024);
    for (int i = threadIdx.x; i < 26*1024; i += 1024) {
        int o = i & 31, c = (i >> 5) & 31, kp = i >> 10;
        int k = kp + (kp >= 13 ? 1 : 0);
        wq[i] = packbf(Wq1[k*1024 + c*32 + o], Wq2[k*1024 + c*32 + o]);
    }
    if (threadIdx.x < 128) lbs[threadIdx.x] = 0.f;
    __syncthreads();

    const int lane = threadIdx.x & 63, o = lane & 31, h = lane >> 5;
    const bool idxlane = (lane < 27 && lane != 13);
    // self (k=13) weights, register-packed bf16x2
    u32 wsr[8], wsq[16];
    #pragma unroll
    for (int cc2 = 0; cc2 < 8; ++cc2)
        wsr[cc2] = packbf(Wr1[13*1024 + (h*16+2*cc2)*32 + o], Wr1[13*1024 + (h*16+2*cc2+1)*32 + o]);
    #pragma unroll
    for (int cc = 0; cc < 16; ++cc)
        wsq[cc] = packbf(Wq1[13*1024 + (h*16+cc)*32 + o], Wq2[13*1024 + (h*16+cc)*32 + o]);
    const float brv = br1[o], b1 = bq1[o], b2 = bq2[o];

    const long long wave = (long long)blockIdx.x*16 + (threadIdx.x>>6);
    long long n0 = wave*CPT, n1 = n0+CPT; if (n1 > N) n1 = N;

    // cross-iter prefetch: only next idx + next self rows
    int cidx = -1; float pselfc = 0.f, pselfg = 0.f;
    if (n0 < n1) {
        cidx = idxlane ? nbr[(long long)lane*N + n0] : -1;
        pselfc = cv[n0*HC + o]; pselfg = gl[n0*HC + o];
    }

    for (long long n = n0; n < n1; ++n) {
        int idxv = cidx;
        float selfc = pselfc, selfg = pselfg;
        u64 mask = __ballot(idxv >= 0);
        // issue first-2 gathers now; hide their latency under self-MACs
        float rc0=0.f, rg0=0.f, rc1=0.f, rg1=0.f;
        u64 m2 = 0;
        if (mask) {
            int k0 = (int)__builtin_ctzll(mask);
            int i0 = __shfl(idxv, k0, 64);
            rc0 = cv[(long long)i0*HC + o]; rg0 = gl[(long long)i0*HC + o];
            m2 = mask & (mask-1);
            if (m2) {
                int k1 = (int)__builtin_ctzll(m2);
                int i1 = __shfl(idxv, k1, 64);
                rc1 = cv[(long long)i1*HC + o]; rg1 = gl[(long long)i1*HC + o];
            }
        }
        // prefetch next-iteration state
        if (n+1 < n1) {
            cidx = idxlane ? nbr[(long long)lane*N + n+1] : -1;
            pselfc = cv[(n+1)*HC + o]; pselfg = gl[(n+1)*HC + o];
        }
        // self MACs
        float accr = 0.f, acc1 = 0.f, acc2 = 0.f;
        #pragma unroll
        for (int cc2 = 0; cc2 < 8; ++cc2) {
            u32 wv = wsr[cc2];
            float xv0 = __shfl(selfc, h*16 + 2*cc2, 64);
            float xv1 = __shfl(selfc, h*16 + 2*cc2 + 1, 64);
            accr = fmaf(u2f(wv << 16), xv0, accr);
            accr = fmaf(u2f(wv & 0xffff0000u), xv1, accr);
        }
        #pragma unroll
        for (int cc = 0; cc < 16; ++cc) {
            u32 wv = wsq[cc];
            float xv = __shfl(selfg, h*16 + cc, 64);
            acc1 = fmaf(u2f(wv << 16), xv, acc1);
            acc2 = fmaf(u2f(wv & 0xffff0000u), xv, acc2);
        }
        // sparse neighbors
        u64 mm = mask; int j = 0;
        while (mm) {
            int k = (int)__builtin_ctzll(mm); mm &= mm-1;
            float rc, rg;
            if (j == 0)      { rc = rc0; rg = rg0; }
            else if (j == 1) { rc = rc1; rg = rg1; }
            else { int ii = __shfl(idxv, k, 64);
                   rc = cv[(long long)ii*HC + o]; rg = gl[(long long)ii*HC + o]; }
            int ks = k - (k > 13 ? 1 : 0);
            const u32* wpr = wr + ks*512 + h*256 + o;
            const u32* wpq = wq + ks*1024 + h*512 + o;
            #pragma unroll
            for (int cc2 = 0; cc2 < 8; ++cc2) {
                u32 wv = wpr[cc2*32];
                float xv0 = __shfl(rc, h*16 + 2*cc2, 64);
                float xv1 = __shfl(rc, h*16 + 2*cc2 + 1, 64);
                accr = fmaf(u2f(wv << 16), xv0, accr);
                accr = fmaf(u2f(wv & 0xffff0000u), xv1, accr);
            }
            #pragma unroll
            for (int cc = 0; cc < 16; ++cc) {
                u32 wv = wpq[cc*32];
                float xv = __shfl(rg, h*16 + cc, 64);
                acc1 = fmaf(u2f(wv << 16), xv, acc1);
                acc2 = fmaf(u2f(wv & 0xffff0000u), xv, acc2);
            }
            ++j;
        }
        accr += __shfl_xor(accr, 32, 64);
        acc1 += __shfl_xor(acc1, 32, 64);
        acc2 += __shfl_xor(acc2, 32, 64);
        float rv = fmaxf(accr + brv, 0.f);
        float o1 = fmaxf(acc1 + b1, 0.f);
        float o2 = fmaxf(acc2 + b2, 0.f);
        float sm = o1;
        #pragma unroll
        for (int d = 1; d < 32; d <<= 1) sm += __shfl_xor(sm, d, 64);
        int b = batch_id[n];
        if (lane < HC) {
            r1[n*HC + o] = rv;
            s12[n*HC + o] = o1 + o2;
            atomicAdd(&lbs[b*HC + o], o2);
        }
        if (lane == 0) m1[n] = sm * (1.f/32.f);
    }
    __syncthreads();
    if (threadIdx.x < 128) atomicAdd(&bsum[threadIdx.x], lbs[threadIdx.x]);
}

// ---- K3 fused: r2-conv -> cx2 tile in LDS -> MFMA epilogue -> out ----
__global__ __launch_bounds__(512, 1) void k3_fused(
    const float* __restrict__ r1, const float* __restrict__ cv,
    const float* __restrict__ gl, const float* __restrict__ s12,
    const float* __restrict__ m1, const float* __restrict__ bsum,
    const int* __restrict__ nbr, const int* __restrict__ batch_id,
    const float* __restrict__ Wr2, const float* __restrict__ br2,
    const float* __restrict__ Wq3, const float* __restrict__ bq3,
    const float* __restrict__ Wg2, const float* __restrict__ bg2,
    const float* __restrict__ x, float* __restrict__ out,
    long long N, const int* __restrict__ bsz)
{
    __shared__ u32 wr[26*512];
    __shared__ __align__(16) u16 finL[8][16*40];
    __shared__ __align__(16) u16 a2L[8][16*72];
    stage_w26(Wr2, wr, 512);
    __syncthreads();

    const int wid = threadIdx.x >> 6;
    u16* fin_bf = finL[wid];
    u16* a2_bf  = a2L[wid];
    const int lane = threadIdx.x & 63, o = lane & 31, h = lane >> 5;
    const int m = lane & 15, g = lane >> 4;
    const bool idxlane = (lane < 27 && lane != 13);

    u32 wsr[8];
    #pragma unroll
    for (int cc2 = 0; cc2 < 8; ++cc2)
        wsr[cc2] = packbf(Wr2[13*1024 + (h*16+2*cc2)*32 + o], Wr2[13*1024 + (h*16+2*cc2+1)*32 + o]);
    const float brv = br2[o];

    const long long wave = (long long)blockIdx.x*8 + wid;
    const long long p0 = wave*CPT;
    long long n0 = p0, n1 = n0+CPT; if (n1 > N) n1 = N;

    // conv phase: cx2 = relu(sconv(r1,Wr2)+br2) + 2*cv -> a2 tile (bf16)
    int cidx = -1; float pself = 0.f, pcv = 0.f;
    if (n0 < n1) {
        cidx = idxlane ? nbr[(long long)lane*N + n0] : -1;
        pself = r1[n0*HC + o]; pcv = cv[n0*HC + o];
    }
    for (long long n = n0; n < n1; ++n) {
        int idxv = cidx;
        float selfv = pself, cvv = pcv;
        u64 mask = __ballot(idxv >= 0);
        float rr0=0.f, rr1=0.f;
        u64 m2 = 0;
        if (mask) {
            int k0 = (int)__builtin_ctzll(mask);
            int i0 = __shfl(idxv, k0, 64);
            rr0 = r1[(long long)i0*HC + o];
            m2 = mask & (mask-1);
            if (m2) {
                int k1 = (int)__builtin_ctzll(m2);
                int i1 = __shfl(idxv, k1, 64);
                rr1 = r1[(long long)i1*HC + o];
            }
        }
        if (n+1 < n1) {
            cidx = idxlane ? nbr[(long long)lane*N + n+1] : -1;
            pself = r1[(n+1)*HC + o]; pcv = cv[(n+1)*HC + o];
        }
        float acc = 0.f;
        #pragma unroll
        for (int cc2 = 0; cc2 < 8; ++cc2) {
            u32 wv = wsr[cc2];
            float xv0 = __shfl(selfv, h*16 + 2*cc2, 64);
            float xv1 = __shfl(selfv, h*16 + 2*cc2 + 1, 64);
            acc = fmaf(u2f(wv << 16), xv0, acc);
            acc = fmaf(u2f(wv & 0xffff0000u), xv1, acc);
        }
        u64 mm = mask; int j = 0;
        while (mm) {
            int k = (int)__builtin_ctzll(mm); mm &= mm-1;
            float rr;
            if (j == 0)      rr = rr0;
            else if (j == 1) rr = rr1;
            else { int ii = __shfl(idxv, k, 64); rr = r1[(long long)ii*HC + o]; }
            int ks = k - (k > 13 ? 1 : 0);
            const u32* wpr = wr + ks*512 + h*256 + o;
            #pragma unroll
            for (int cc2 = 0; cc2 < 8; ++cc2) {
                u32 wv = wpr[cc2*32];
                float xv0 = __shfl(rr, h*16 + 2*cc2, 64);
                float xv1 = __shfl(rr, h*16 + 2*cc2 + 1, 64);
                acc = fmaf(u2f(wv << 16), xv0, acc);
                acc = fmaf(u2f(wv & 0xffff0000u), xv1, acc);
            }
            ++j;
        }
        acc += __shfl_xor(acc, 32, 64);
        float cx2 = fmaxf(acc + brv, 0.f) + 2.f*cvv;
        if (lane < HC) a2_bf[(int)(n - p0)*72 + o] = f2bf(cx2);
    }
    if (p0 >= N) return;

    // epilogue (MFMA)
    bf16x8 bq[2];
    #pragma unroll
    for (int no = 0; no < 2; ++no)
      #pragma unroll
      for (int j = 0; j < 8; ++j)
        bq[no][j] = bfs(Wq3[(g*8+j)*32 + no*16 + m]);
    bf16x8 bgw[4][2];
    #pragma unroll
    for (int no = 0; no < 4; ++no)
      #pragma unroll
      for (int kf = 0; kf < 2; ++kf)
        #pragma unroll
        for (int j = 0; j < 8; ++j)
          bgw[no][kf][j] = bfs(Wg2[(kf*32 + g*8 + j)*64 + no*16 + m]);
    const float bq3a = bq3[m], bq3b = bq3[16+m];
    float bgb[4];
    #pragma unroll
    for (int no = 0; no < 4; ++no) bgb[no] = bg2[no*16 + m];
    const float invNP = (float)(*bsz) / (float)N;
    const int p_lin = lane >> 2, c0 = (lane & 3) * 8;

    {
        long long pp = p0 + p_lin; if (pp > N-1) pp = N-1;
        float m1v = m1[pp];
        int b = batch_id[pp];
        const float4* bsp = (const float4*)(bsum + b*32 + c0);
        float4 bs0 = bsp[0], bs1 = bsp[1];
        const float4* s12p = (const float4*)(s12 + pp*32 + c0);
        float4 s0 = s12p[0], s1 = s12p[1];
        float bsv[8] = {bs0.x,bs0.y,bs0.z,bs0.w,bs1.x,bs1.y,bs1.z,bs1.w};
        float sv[8]  = {s0.x,s0.y,s0.z,s0.w,s1.x,s1.y,s1.z,s1.w};
        bf16x8 fbv;
        #pragma unroll
        for (int j = 0; j < 8; ++j) {
            float enc = sqrtf(m1v * bsv[j] * invNP + 1e-12f);
            fbv[j] = bfs(enc + sv[j]);
        }
        *(bf16x8*)&fin_bf[p_lin*40 + c0] = fbv;
    }
    asm volatile("s_waitcnt lgkmcnt(0)" ::: "memory");
    bf16x8 af = *(const bf16x8*)&fin_bf[m*40 + g*8];
    f32x4 f0 = {0.f,0.f,0.f,0.f}, f1 = {0.f,0.f,0.f,0.f};
    f0 = __builtin_amdgcn_mfma_f32_16x16x32_bf16(af, bq[0], f0, 0,0,0);
    f1 = __builtin_amdgcn_mfma_f32_16x16x32_bf16(af, bq[1], f1, 0,0,0);
    #pragma unroll
    for (int j = 0; j < 4; ++j) {
        int row = g*4 + j;
        long long pr = p0 + row; if (pr > N-1) pr = N-1;
        float fa = fmaxf(f0[j] + bq3a, 0.f);
        float fb = fmaxf(f1[j] + bq3b, 0.f);
        float g0 = fmaxf(gl[pr*32 + m] - fa, 0.f);
        float g1 = fmaxf(gl[pr*32 + 16 + m] - fb, 0.f);
        a2_bf[row*72 + 32 + m] = f2bf(g0);
        a2_bf[row*72 + 48 + m] = f2bf(g1);
    }
    asm volatile("s_waitcnt lgkmcnt(0)" ::: "memory");
    bf16x8 a20 = *(const bf16x8*)&a2_bf[m*72 + g*8];
    bf16x8 a21 = *(const bf16x8*)&a2_bf[m*72 + 32 + g*8];
    #pragma unroll
    for (int no = 0; no < 4; ++no) {
        f32x4 acc = {0.f,0.f,0.f,0.f};
        acc = __builtin_amdgcn_mfma_f32_16x16x32_bf16(a20, bgw[no][0], acc, 0,0,0);
        acc = __builtin_amdgcn_mfma_f32_16x16x32_bf16(a21, bgw[no][1], acc, 0,0,0);
        #pragma unroll
        for (int j = 0; j < 4; ++j) {
            long long pr = p0 + g*4 + j;
            if (pr < N)
                out[pr*64 + no*16 + m] = x[pr*64 + no*16 + m] + acc[j] + bgb[no];
        }
    }
}

extern "C" void kernel_launch(void* const* d_in, const int* in_sizes, int n_in,
                              void* d_out, int out_size, void* d_ws, size_t ws_size,
                              hipStream_t stream) {
    const float* x   = (const float*)d_in[0];
    const float* Wg1 = (const float*)d_in[1];
    const float* bg1 = (const float*)d_in[2];
    const float* Wg2 = (const float*)d_in[3];
    const float* bg2 = (const float*)d_in[4];
    const float* Wr1 = (const float*)d_in[5];
    const float* br1 = (const float*)d_in[6];
    const float* Wr2 = (const float*)d_in[7];
    const float* br2 = (const float*)d_in[8];
    const float* Wq1 = (const float*)d_in[9];
    const float* bq1 = (const float*)d_in[10];
    const float* Wq2 = (const float*)d_in[11];
    const float* bq2 = (const float*)d_in[12];
    const float* Wq3 = (const float*)d_in[13];
    const float* bq3 = (const float*)d_in[14];
    const int* nbr   = (const int*)d_in[15];
    const int* bid   = (const int*)d_in[16];
    const int* bsz   = (const int*)d_in[17];

    const long long N = (long long)in_sizes[0] / 64;

    float* cv   = (float*)d_ws;
    float* gl   = cv  + N * 32;
    float* r1   = gl  + N * 32;
    float* s12  = r1  + N * 32;
    float* m1   = s12 + N * 32;
    float* bsum = m1  + N;               // 128 floats used

    float* out = (float*)d_out;

    hipMemsetAsync(bsum, 0, 128 * sizeof(float), stream);

    long long tiles = (N + 15) / 16;
    long long gwaves = (tiles + 3) / 4;
    int gblocks = (int)((gwaves + 3) / 4);
    k1_mfma<<<gblocks, 256, 0, stream>>>(x, Wg1, bg1, cv, gl, N);

    long long cwaves = (N + CPT - 1) / CPT;
    int blk16 = (int)((cwaves + 15) / 16);
    int blk8  = (int)((cwaves + 7) / 8);
    k2_fused<<<blk16, 1024, 0, stream>>>(cv, gl, nbr, bid, Wr1, br1, Wq1, bq1, Wq2, bq2,
                                         r1, s12, m1, bsum, N);
    k3_fused<<<blk8, 512, 0, stream>>>(r1, cv, gl, s12, m1, bsum, nbr, bid,
                                       Wr2, br2, Wq3, bq3, Wg2, bg2, x, out, N, bsz);
}

// Round 9
// 397.488 us; speedup vs baseline: 2.2873x; 1.6292x over previous
//
#include <hip/hip_runtime.h>
#include <stdint.h>

typedef unsigned int u32;
typedef unsigned short u16;
typedef unsigned long long u64;
typedef __attribute__((ext_vector_type(8))) short bf16x8;
typedef __attribute__((ext_vector_type(4))) float f32x4;

#define HC 32
#define CPT 16   // points per wave in conv kernels

__device__ __forceinline__ float u2f(u32 u){ union{u32 i;float f;}v; v.i=u; return v.f; }
__device__ __forceinline__ u16 f2bf(float f){ union{float f;u32 i;}v; v.f=f; u32 i=v.i;
    return (u16)((i + 0x7FFFu + ((i>>16)&1u))>>16); }  // RNE
__device__ __forceinline__ short bfs(float f){ return (short)f2bf(f); }
__device__ __forceinline__ u32 packbf(float a, float b){ return (u32)f2bf(a) | ((u32)f2bf(b)<<16); }

// stage 26 sparse k-slices (skip k=13) of one 27x32x32 matrix, bf16x2 c-pairs
__device__ __forceinline__ void stage_w26(const float* __restrict__ W, u32* __restrict__ wl, int nthr) {
    for (int i = threadIdx.x; i < 26*512; i += nthr) {
        int o = i & 31, row = (i >> 5) & 15, kp = i >> 9;
        int k = kp + (kp >= 13 ? 1 : 0);
        int c0 = (row >> 3)*16 + (row & 7)*2;
        wl[i] = packbf(W[k*1024 + c0*32 + o], W[k*1024 + (c0+1)*32 + o]);
    }
}

// ---- K1: y = x @ Wg1 + bg1 -> cv | gl  (MFMA) ----
__global__ __launch_bounds__(256) void k1_mfma(
    const float* __restrict__ x, const float* __restrict__ Wg1, const float* __restrict__ bg1,
    float* __restrict__ cv, float* __restrict__ gl, long long N)
{
    const int lane = threadIdx.x & 63;
    const int m = lane & 15, g = lane >> 4;
    bf16x8 bw[4][2];
    #pragma unroll
    for (int no = 0; no < 4; ++no)
      #pragma unroll
      for (int kf = 0; kf < 2; ++kf)
        #pragma unroll
        for (int j = 0; j < 8; ++j)
            bw[no][kf][j] = bfs(Wg1[(kf*32 + g*8 + j)*64 + no*16 + m]);
    float bias4[4];
    #pragma unroll
    for (int no = 0; no < 4; ++no) bias4[no] = bg1[no*16 + m];

    const long long wave = (long long)blockIdx.x*4 + (threadIdx.x>>6);
    long long t0 = wave * 4;
    #pragma unroll 1
    for (long long t = t0; t < t0+4; ++t) {
        long long p0 = t*16;
        if (p0 >= N) break;
        long long pr_a = p0 + m; if (pr_a > N-1) pr_a = N-1;
        const float4* xr = (const float4*)(x + pr_a*64);
        bf16x8 aw[2];
        #pragma unroll
        for (int kf = 0; kf < 2; ++kf) {
            float4 lo = xr[kf*8 + g*2];
            float4 hi = xr[kf*8 + g*2 + 1];
            aw[kf][0]=bfs(lo.x); aw[kf][1]=bfs(lo.y); aw[kf][2]=bfs(lo.z); aw[kf][3]=bfs(lo.w);
            aw[kf][4]=bfs(hi.x); aw[kf][5]=bfs(hi.y); aw[kf][6]=bfs(hi.z); aw[kf][7]=bfs(hi.w);
        }
        #pragma unroll
        for (int no = 0; no < 4; ++no) {
            f32x4 acc = {0.f,0.f,0.f,0.f};
            acc = __builtin_amdgcn_mfma_f32_16x16x32_bf16(aw[0], bw[no][0], acc, 0,0,0);
            acc = __builtin_amdgcn_mfma_f32_16x16x32_bf16(aw[1], bw[no][1], acc, 0,0,0);
            #pragma unroll
            for (int j = 0; j < 4; ++j) {
                long long pr = p0 + g*4 + j;
                if (pr < N) {
                    float v = acc[j] + bias4[no];
                    if (no < 2) cv[pr*32 + no*16 + m] = v;
                    else        gl[pr*32 + (no-2)*16 + m] = v;
                }
            }
        }
    }
}

// ---- K2a: r1 = relu(sconv(cv, Wr1) + br1) ; 2-deep gather pipeline ----
__global__ __launch_bounds__(512, 4) void k2a_conv(
    const float* __restrict__ cv, const int* __restrict__ nbr,
    const float* __restrict__ Wr1, const float* __restrict__ br1,
    float* __restrict__ r1, long long N)
{
    __shared__ u32 wr[26*512];
    stage_w26(Wr1, wr, 512);
    __syncthreads();
    const int lane = threadIdx.x & 63, o = lane & 31, h = lane >> 5;
    const bool idxlane = (lane < 27 && lane != 13);
    u32 wsr[8];
    #pragma unroll
    for (int cc2 = 0; cc2 < 8; ++cc2)
        wsr[cc2] = packbf(Wr1[13*1024 + (h*16+2*cc2)*32 + o], Wr1[13*1024 + (h*16+2*cc2+1)*32 + o]);
    const float brv = br1[o];

    const long long wave = (long long)blockIdx.x*8 + (threadIdx.x>>6);
    long long n0 = wave*CPT, n1 = n0+CPT; if (n1 > N) n1 = N;
    if (n0 >= n1) return;

    // prime pipeline for point n0 (+ idx for n0+1)
    int ia = idxlane ? nbr[(long long)lane*N + n0] : -1;
    int ib = (n0+1 < n1 && idxlane) ? nbr[(long long)lane*N + n0+1] : -1;
    u64 ma = __ballot(ia >= 0);
    float sa = cv[n0*HC + o];
    float ra0 = 0.f, ra1 = 0.f;
    if (ma) {
        int k0 = (int)__builtin_ctzll(ma);
        ra0 = cv[(long long)__shfl(ia, k0, 64)*HC + o];
        u64 m2 = ma & (ma-1);
        if (m2) ra1 = cv[(long long)__shfl(ia, (int)__builtin_ctzll(m2), 64)*HC + o];
    }

    for (long long n = n0; n < n1; ++n) {
        // prefetch point n+1 (ballot + first-2 rows + self), idx for n+2
        u64 mb = 0; float rb0 = 0.f, rb1 = 0.f, sb = 0.f; int ic = -1;
        if (n+1 < n1) {
            mb = __ballot(ib >= 0);
            sb = cv[(n+1)*HC + o];
            if (mb) {
                int k0 = (int)__builtin_ctzll(mb);
                rb0 = cv[(long long)__shfl(ib, k0, 64)*HC + o];
                u64 m2 = mb & (mb-1);
                if (m2) rb1 = cv[(long long)__shfl(ib, (int)__builtin_ctzll(m2), 64)*HC + o];
            }
            if (n+2 < n1) ic = idxlane ? nbr[(long long)lane*N + n+2] : -1;
        }
        // compute point n
        float accr = 0.f;
        #pragma unroll
        for (int cc2 = 0; cc2 < 8; ++cc2) {
            u32 wv = wsr[cc2];
            float xv0 = __shfl(sa, h*16 + 2*cc2, 64);
            float xv1 = __shfl(sa, h*16 + 2*cc2 + 1, 64);
            accr = fmaf(u2f(wv << 16), xv0, accr);
            accr = fmaf(u2f(wv & 0xffff0000u), xv1, accr);
        }
        u64 mm = ma; int j = 0;
        while (mm) {
            int k = (int)__builtin_ctzll(mm); mm &= mm-1;
            float rr;
            if (j == 0)      rr = ra0;
            else if (j == 1) rr = ra1;
            else rr = cv[(long long)__shfl(ia, k, 64)*HC + o];
            int ks = k - (k > 13 ? 1 : 0);
            const u32* wpr = wr + ks*512 + h*256 + o;
            #pragma unroll
            for (int cc2 = 0; cc2 < 8; ++cc2) {
                u32 wv = wpr[cc2*32];
                float xv0 = __shfl(rr, h*16 + 2*cc2, 64);
                float xv1 = __shfl(rr, h*16 + 2*cc2 + 1, 64);
                accr = fmaf(u2f(wv << 16), xv0, accr);
                accr = fmaf(u2f(wv & 0xffff0000u), xv1, accr);
            }
            ++j;
        }
        accr += __shfl_xor(accr, 32, 64);
        if (lane < HC) r1[n*HC + o] = fmaxf(accr + brv, 0.f);
        // rotate
        ia = ib; ib = ic; ma = mb; ra0 = rb0; ra1 = rb1; sa = sb;
    }
}

// ---- K2b: out1/out2 q-convs fused; s12, m1, bsum ; 2-deep gather pipeline ----
__global__ __launch_bounds__(1024, 4) void k2b_conv(
    const float* __restrict__ gl, const int* __restrict__ nbr,
    const float* __restrict__ Wq1, const float* __restrict__ bq1,
    const float* __restrict__ Wq2, const float* __restrict__ bq2,
    const int* __restrict__ batch_id,
    float* __restrict__ s12, float* __restrict__ m1, float* __restrict__ bsum,
    long long N)
{
    __shared__ u32 wq[26*1024];   // (Wq1,Wq2) packed per (c,o)
    __shared__ float lbs[128];
    for (int i = threadIdx.x; i < 26*1024; i += 1024) {
        int o = i & 31, c = (i >> 5) & 31, kp = i >> 10;
        int k = kp + (kp >= 13 ? 1 : 0);
        wq[i] = packbf(Wq1[k*1024 + c*32 + o], Wq2[k*1024 + c*32 + o]);
    }
    if (threadIdx.x < 128) lbs[threadIdx.x] = 0.f;
    __syncthreads();

    const int lane = threadIdx.x & 63, o = lane & 31, h = lane >> 5;
    const bool idxlane = (lane < 27 && lane != 13);
    u32 wsq[16];   // packed bf16 (Wq1,Wq2) self weights
    #pragma unroll
    for (int cc = 0; cc < 16; ++cc)
        wsq[cc] = packbf(Wq1[13*1024 + (h*16+cc)*32 + o], Wq2[13*1024 + (h*16+cc)*32 + o]);
    const float b1 = bq1[o], b2 = bq2[o];

    const long long wave = (long long)blockIdx.x*16 + (threadIdx.x>>6);
    long long n0 = wave*CPT, n1 = n0+CPT; if (n1 > N) n1 = N;
    if (n0 >= n1) return;

    int ia = idxlane ? nbr[(long long)lane*N + n0] : -1;
    int ib = (n0+1 < n1 && idxlane) ? nbr[(long long)lane*N + n0+1] : -1;
    u64 ma = __ballot(ia >= 0);
    float sa = gl[n0*HC + o];
    float ra0 = 0.f, ra1 = 0.f;
    if (ma) {
        int k0 = (int)__builtin_ctzll(ma);
        ra0 = gl[(long long)__shfl(ia, k0, 64)*HC + o];
        u64 m2 = ma & (ma-1);
        if (m2) ra1 = gl[(long long)__shfl(ia, (int)__builtin_ctzll(m2), 64)*HC + o];
    }

    for (long long n = n0; n < n1; ++n) {
        u64 mb = 0; float rb0 = 0.f, rb1 = 0.f, sb = 0.f; int ic = -1;
        if (n+1 < n1) {
            mb = __ballot(ib >= 0);
            sb = gl[(n+1)*HC + o];
            if (mb) {
                int k0 = (int)__builtin_ctzll(mb);
                rb0 = gl[(long long)__shfl(ib, k0, 64)*HC + o];
                u64 m2 = mb & (mb-1);
                if (m2) rb1 = gl[(long long)__shfl(ib, (int)__builtin_ctzll(m2), 64)*HC + o];
            }
            if (n+2 < n1) ic = idxlane ? nbr[(long long)lane*N + n+2] : -1;
        }
        float acc1 = 0.f, acc2 = 0.f;
        #pragma unroll
        for (int cc = 0; cc < 16; ++cc) {
            u32 wv = wsq[cc];
            float xv = __shfl(sa, h*16 + cc, 64);
            acc1 = fmaf(u2f(wv << 16), xv, acc1);
            acc2 = fmaf(u2f(wv & 0xffff0000u), xv, acc2);
        }
        u64 mm = ma; int j = 0;
        while (mm) {
            int k = (int)__builtin_ctzll(mm); mm &= mm-1;
            float rg;
            if (j == 0)      rg = ra0;
            else if (j == 1) rg = ra1;
            else rg = gl[(long long)__shfl(ia, k, 64)*HC + o];
            int ks = k - (k > 13 ? 1 : 0);
            const u32* wpq = wq + ks*1024 + h*512 + o;
            #pragma unroll
            for (int cc = 0; cc < 16; ++cc) {
                u32 wv = wpq[cc*32];
                float xv = __shfl(rg, h*16 + cc, 64);
                acc1 = fmaf(u2f(wv << 16), xv, acc1);
                acc2 = fmaf(u2f(wv & 0xffff0000u), xv, acc2);
            }
            ++j;
        }
        acc1 += __shfl_xor(acc1, 32, 64);
        acc2 += __shfl_xor(acc2, 32, 64);
        float o1 = fmaxf(acc1 + b1, 0.f);
        float o2 = fmaxf(acc2 + b2, 0.f);
        float sm = o1;
        #pragma unroll
        for (int d = 1; d < 32; d <<= 1) sm += __shfl_xor(sm, d, 64);
        int b = batch_id[n];
        if (lane < HC) {
            s12[n*HC + o] = o1 + o2;
            atomicAdd(&lbs[b*HC + o], o2);
        }
        if (lane == 0) m1[n] = sm * (1.f/32.f);
        ia = ib; ib = ic; ma = mb; ra0 = rb0; ra1 = rb1; sa = sb;
    }
    __syncthreads();
    if (threadIdx.x < 128) atomicAdd(&bsum[threadIdx.x], lbs[threadIdx.x]);
}

// ---- K3 fused: r2-conv -> cx2 tile in LDS -> MFMA epilogue -> out ----
__global__ __launch_bounds__(512, 1) void k3_fused(
    const float* __restrict__ r1, const float* __restrict__ cv,
    const float* __restrict__ gl, const float* __restrict__ s12,
    const float* __restrict__ m1, const float* __restrict__ bsum,
    const int* __restrict__ nbr, const int* __restrict__ batch_id,
    const float* __restrict__ Wr2, const float* __restrict__ br2,
    const float* __restrict__ Wq3, const float* __restrict__ bq3,
    const float* __restrict__ Wg2, const float* __restrict__ bg2,
    const float* __restrict__ x, float* __restrict__ out,
    long long N, const int* __restrict__ bsz)
{
    __shared__ u32 wr[26*512];
    __shared__ __align__(16) u16 finL[8][16*40];
    __shared__ __align__(16) u16 a2L[8][16*72];
    stage_w26(Wr2, wr, 512);
    __syncthreads();

    const int wid = threadIdx.x >> 6;
    u16* fin_bf = finL[wid];
    u16* a2_bf  = a2L[wid];
    const int lane = threadIdx.x & 63, o = lane & 31, h = lane >> 5;
    const int m = lane & 15, g = lane >> 4;
    const bool idxlane = (lane < 27 && lane != 13);

    u32 wsr[8];
    #pragma unroll
    for (int cc2 = 0; cc2 < 8; ++cc2)
        wsr[cc2] = packbf(Wr2[13*1024 + (h*16+2*cc2)*32 + o], Wr2[13*1024 + (h*16+2*cc2+1)*32 + o]);
    const float brv = br2[o];

    const long long wave = (long long)blockIdx.x*8 + wid;
    const long long p0 = wave*CPT;
    long long n0 = p0, n1 = n0+CPT; if (n1 > N) n1 = N;

    // conv phase: cx2 = relu(sconv(r1,Wr2)+br2) + 2*cv -> a2 tile (bf16)
    int cidx = -1; float pself = 0.f, pcv = 0.f;
    if (n0 < n1) {
        cidx = idxlane ? nbr[(long long)lane*N + n0] : -1;
        pself = r1[n0*HC + o]; pcv = cv[n0*HC + o];
    }
    for (long long n = n0; n < n1; ++n) {
        int idxv = cidx;
        float selfv = pself, cvv = pcv;
        u64 mask = __ballot(idxv >= 0);
        float rr0=0.f, rr1=0.f;
        u64 m2 = 0;
        if (mask) {
            int k0 = (int)__builtin_ctzll(mask);
            rr0 = r1[(long long)__shfl(idxv, k0, 64)*HC + o];
            m2 = mask & (mask-1);
            if (m2) rr1 = r1[(long long)__shfl(idxv, (int)__builtin_ctzll(m2), 64)*HC + o];
        }
        if (n+1 < n1) {
            cidx = idxlane ? nbr[(long long)lane*N + n+1] : -1;
            pself = r1[(n+1)*HC + o]; pcv = cv[(n+1)*HC + o];
        }
        float acc = 0.f;
        #pragma unroll
        for (int cc2 = 0; cc2 < 8; ++cc2) {
            u32 wv = wsr[cc2];
            float xv0 = __shfl(selfv, h*16 + 2*cc2, 64);
            float xv1 = __shfl(selfv, h*16 + 2*cc2 + 1, 64);
            acc = fmaf(u2f(wv << 16), xv0, acc);
            acc = fmaf(u2f(wv & 0xffff0000u), xv1, acc);
        }
        u64 mm = mask; int j = 0;
        while (mm) {
            int k = (int)__builtin_ctzll(mm); mm &= mm-1;
            float rr;
            if (j == 0)      rr = rr0;
            else if (j == 1) rr = rr1;
            else rr = r1[(long long)__shfl(idxv, k, 64)*HC + o];
            int ks = k - (k > 13 ? 1 : 0);
            const u32* wpr = wr + ks*512 + h*256 + o;
            #pragma unroll
            for (int cc2 = 0; cc2 < 8; ++cc2) {
                u32 wv = wpr[cc2*32];
                float xv0 = __shfl(rr, h*16 + 2*cc2, 64);
                float xv1 = __shfl(rr, h*16 + 2*cc2 + 1, 64);
                acc = fmaf(u2f(wv << 16), xv0, acc);
                acc = fmaf(u2f(wv & 0xffff0000u), xv1, acc);
            }
            ++j;
        }
        acc += __shfl_xor(acc, 32, 64);
        float cx2 = fmaxf(acc + brv, 0.f) + 2.f*cvv;
        if (lane < HC) a2_bf[(int)(n - p0)*72 + o] = f2bf(cx2);
    }
    if (p0 >= N) return;

    // epilogue (MFMA)
    bf16x8 bq[2];
    #pragma unroll
    for (int no = 0; no < 2; ++no)
      #pragma unroll
      for (int j = 0; j < 8; ++j)
        bq[no][j] = bfs(Wq3[(g*8+j)*32 + no*16 + m]);
    bf16x8 bgw[4][2];
    #pragma unroll
    for (int no = 0; no < 4; ++no)
      #pragma unroll
      for (int kf = 0; kf < 2; ++kf)
        #pragma unroll
        for (int j = 0; j < 8; ++j)
          bgw[no][kf][j] = bfs(Wg2[(kf*32 + g*8 + j)*64 + no*16 + m]);
    const float bq3a = bq3[m], bq3b = bq3[16+m];
    float bgb[4];
    #pragma unroll
    for (int no = 0; no < 4; ++no) bgb[no] = bg2[no*16 + m];
    const float invNP = (float)(*bsz) / (float)N;
    const int p_lin = lane >> 2, c0 = (lane & 3) * 8;

    {
        long long pp = p0 + p_lin; if (pp > N-1) pp = N-1;
        float m1v = m1[pp];
        int b = batch_id[pp];
        const float4* bsp = (const float4*)(bsum + b*32 + c0);
        float4 bs0 = bsp[0], bs1 = bsp[1];
        const float4* s12p = (const float4*)(s12 + pp*32 + c0);
        float4 s0 = s12p[0], s1 = s12p[1];
        float bsv[8] = {bs0.x,bs0.y,bs0.z,bs0.w,bs1.x,bs1.y,bs1.z,bs1.w};
        float sv[8]  = {s0.x,s0.y,s0.z,s0.w,s1.x,s1.y,s1.z,s1.w};
        bf16x8 fbv;
        #pragma unroll
        for (int j = 0; j < 8; ++j) {
            float enc = sqrtf(m1v * bsv[j] * invNP + 1e-12f);
            fbv[j] = bfs(enc + sv[j]);
        }
        *(bf16x8*)&fin_bf[p_lin*40 + c0] = fbv;
    }
    asm volatile("s_waitcnt lgkmcnt(0)" ::: "memory");
    bf16x8 af = *(const bf16x8*)&fin_bf[m*40 + g*8];
    f32x4 f0 = {0.f,0.f,0.f,0.f}, f1 = {0.f,0.f,0.f,0.f};
    f0 = __builtin_amdgcn_mfma_f32_16x16x32_bf16(af, bq[0], f0, 0,0,0);
    f1 = __builtin_amdgcn_mfma_f32_16x16x32_bf16(af, bq[1], f1, 0,0,0);
    #pragma unroll
    for (int j = 0; j < 4; ++j) {
        int row = g*4 + j;
        long long pr = p0 + row; if (pr > N-1) pr = N-1;
        float fa = fmaxf(f0[j] + bq3a, 0.f);
        float fb = fmaxf(f1[j] + bq3b, 0.f);
        float g0 = fmaxf(gl[pr*32 + m] - fa, 0.f);
        float g1 = fmaxf(gl[pr*32 + 16 + m] - fb, 0.f);
        a2_bf[row*72 + 32 + m] = f2bf(g0);
        a2_bf[row*72 + 48 + m] = f2bf(g1);
    }
    asm volatile("s_waitcnt lgkmcnt(0)" ::: "memory");
    bf16x8 a20 = *(const bf16x8*)&a2_bf[m*72 + g*8];
    bf16x8 a21 = *(const bf16x8*)&a2_bf[m*72 + 32 + g*8];
    #pragma unroll
    for (int no = 0; no < 4; ++no) {
        f32x4 acc = {0.f,0.f,0.f,0.f};
        acc = __builtin_amdgcn_mfma_f32_16x16x32_bf16(a20, bgw[no][0], acc, 0,0,0);
        acc = __builtin_amdgcn_mfma_f32_16x16x32_bf16(a21, bgw[no][1], acc, 0,0,0);
        #pragma unroll
        for (int j = 0; j < 4; ++j) {
            long long pr = p0 + g*4 + j;
            if (pr < N)
                out[pr*64 + no*16 + m] = x[pr*64 + no*16 + m] + acc[j] + bgb[no];
        }
    }
}

extern "C" void kernel_launch(void* const* d_in, const int* in_sizes, int n_in,
                              void* d_out, int out_size, void* d_ws, size_t ws_size,
                              hipStream_t stream) {
    const float* x   = (const float*)d_in[0];
    const float* Wg1 = (const float*)d_in[1];
    const float* bg1 = (const float*)d_in[2];
    const float* Wg2 = (const float*)d_in[3];
    const float* bg2 = (const float*)d_in[4];
    const float* Wr1 = (const float*)d_in[5];
    const float* br1 = (const float*)d_in[6];
    const float* Wr2 = (const float*)d_in[7];
    const float* br2 = (const float*)d_in[8];
    const float* Wq1 = (const float*)d_in[9];
    const float* bq1 = (const float*)d_in[10];
    const float* Wq2 = (const float*)d_in[11];
    const float* bq2 = (const float*)d_in[12];
    const float* Wq3 = (const float*)d_in[13];
    const float* bq3 = (const float*)d_in[14];
    const int* nbr   = (const int*)d_in[15];
    const int* bid   = (const int*)d_in[16];
    const int* bsz   = (const int*)d_in[17];

    const long long N = (long long)in_sizes[0] / 64;

    float* cv   = (float*)d_ws;
    float* gl   = cv  + N * 32;
    float* r1   = gl  + N * 32;
    float* s12  = r1  + N * 32;
    float* m1   = s12 + N * 32;
    float* bsum = m1  + N;               // 128 floats used

    float* out = (float*)d_out;

    hipMemsetAsync(bsum, 0, 128 * sizeof(float), stream);

    long long tiles = (N + 15) / 16;
    long long gwaves = (tiles + 3) / 4;
    int gblocks = (int)((gwaves + 3) / 4);
    k1_mfma<<<gblocks, 256, 0, stream>>>(x, Wg1, bg1, cv, gl, N);

    long long cwaves = (N + CPT - 1) / CPT;
    int blk8  = (int)((cwaves + 7) / 8);
    int blk16 = (int)((cwaves + 15) / 16);
    k2a_conv<<<blk8, 512, 0, stream>>>(cv, nbr, Wr1, br1, r1, N);
    k2b_conv<<<blk16, 1024, 0, stream>>>(gl, nbr, Wq1, bq1, Wq2, bq2, bid, s12, m1, bsum, N);
    k3_fused<<<blk8, 512, 0, stream>>>(r1, cv, gl, s12, m1, bsum, nbr, bid,
                                       Wr2, br2, Wq3, bq3, Wg2, bg2, x, out, N, bsz);
}